// Round 11
// baseline (75.102 us; speedup 1.0000x reference)
//
#include <hip/hip_runtime.h>
#include <math.h>

// Problem constants (fixed by reference)
constexpr int N_ = 4, P_ = 64, Z_ = 32, Y_ = 128, X_ = 128;
constexpr float EPSF = 1e-8f;
constexpr float INV2S2 = 0.125f;   // 1/(2*sigma^2), sigma = 2

typedef short v8s __attribute__((ext_vector_type(8)));  // 8 bf16 (4 VGPRs)
typedef float v4f __attribute__((ext_vector_type(4)));  // MFMA C/D

// fp32 -> bf16 (RNE). bf16 keeps fp32's exponent: no far-field flush (w can
// be ~1e8 and K ~1e-30; both representable). R10 measured absmax 0.0.
__device__ __forceinline__ short bf16(float f) {
    unsigned u = __float_as_uint(f);
    u = u + 0x7fffu + ((u >> 16) & 1u);
    return (short)(u >> 16);
}

// ---------------------------------------------------------------------------
// MFMA main kernel (R10 structure, x-split for 2 blocks/CU + atomic-m tail).
// Grid: 512 blocks = (n, z, y-half, x-half); 256 threads = 4 waves.
// Per block (y-slab 64 rows x x-half 64 cols):
//   GEMM1 (mfma_f32_16x16x32_bf16): denom[y][x] = sum_p kzy[y][p]*kx[p][x]
//          M=64 y (wave w owns M-tile w), N=64 x-local (4 tiles), K=64 (2 steps).
//   W[y][x] = sigmoid(logit)/max(denom,EPS) -> bf16 LDS (layout transform).
//   GEMM2: D2[p][y] = sum_{x in half} kx[p][x]*W[y][x]
//          M=64 p (wave w owns M-tile w), N=64 y (4 tiles), K=64 (2 steps).
//   s[p] += sum_y kzy[y][p]*D2[p][y]  (in-register, analytic kzy), then
//   fp32 atomicAdd into m[n*64+p] on the 0xAA-poisoned base (-3.03e-13 bias,
//   negligible; R8 verified this exact pattern absmax 0.0 — it was the
//   __threadfence that cost +23 us there, and there is NO fence here).
// Fragment layouts (docs, HW-verified in R10): A[m=lane&15][k=quad*8+j],
// B[k=quad*8+j][n=lane&15], C/D col=lane&15, row=quad*4+reg.
// kx/W tiles XOR-chunk-swizzled (c ^= row&7): 16 fragment rows -> 8 chunks
// -> 2-way LDS aliasing (free) instead of 16-way conflicts.
// 512 blocks = 2/CU so one block's GEMM phases overlap the other's barrier
// drains and logit-load latency (R10 ran 1/CU with serial phases).
// ---------------------------------------------------------------------------
__global__ __launch_bounds__(256) void k_main(const float* __restrict__ logits,
                                              const float* __restrict__ pts,
                                              float* __restrict__ mAcc) {
    const int b = blockIdx.x;          // [n:2][z:5][yh:1][xh:1]
    const int n  = b >> 7;
    const int z  = (b >> 2) & 31;
    const int y0 = ((b >> 1) & 1) * 64;
    const int x0 = (b & 1) * 64;

    const int tid  = threadIdx.x;
    const int lane = tid & 63;
    const int w    = tid >> 6;         // wave 0..3
    const int m    = lane & 15;        // row/col-in-tile index
    const int quad = lane >> 4;        // 0..3

    __shared__ float ptsn[192];        // pts[n] = [64][3]
    __shared__ short kxTB[64 * 64];    // [x-local][p] bf16, 8-chunk XOR swizzle
    __shared__ short WB[64 * 64];      // [y-local][x-local] bf16, same swizzle

    if (tid < 192) ptsn[tid] = pts[n * 192 + tid];
    __syncthreads();

    // kx tile: 4096 exps / 256 threads = 16 per thread, swizzled store.
    for (int i = tid; i < 64 * 64; i += 256) {
        int xl = i >> 6, p = i & 63;
        float dx = (float)(x0 + xl) - ptsn[p * 3 + 2];
        float e = __expf(-dx * dx * INV2S2);
        kxTB[xl * 64 + (((p >> 3) ^ (xl & 7)) * 8) + (p & 7)] = bf16(e);
    }

    // GEMM1 A-frags (kzy row y = y0+w*16+m) analytically: 16 exps/lane.
    v8s a1[2];
    {
        float yv = (float)(y0 + w * 16 + m);
        #pragma unroll
        for (int ks = 0; ks < 2; ++ks) {
            #pragma unroll
            for (int j = 0; j < 8; ++j) {
                int p = ks * 32 + quad * 8 + j;
                float dz = (float)z - ptsn[p * 3 + 0];
                float dy = yv - ptsn[p * 3 + 1];
                a1[ks][j] = bf16(__expf(-(dz * dz + dy * dy) * INV2S2));
            }
        }
    }
    __syncthreads();                   // kxTB ready

    // GEMM1: wave w -> M-tile w (y), N-tiles 0..3 (x-local), K = 2 steps (p).
    v4f acc1[4];
    #pragma unroll
    for (int nt = 0; nt < 4; ++nt) acc1[nt] = (v4f)(0.f);
    #pragma unroll
    for (int ks = 0; ks < 2; ++ks) {
        #pragma unroll
        for (int nt = 0; nt < 4; ++nt) {
            int row = nt * 16 + m;     // x-local
            int c = ks * 4 + quad;     // p-chunk
            v8s bf = *(const v8s*)&kxTB[row * 64 + ((c ^ (row & 7)) * 8)];
            acc1[nt] = __builtin_amdgcn_mfma_f32_16x16x32_bf16(a1[ks], bf, acc1[nt], 0, 0, 0);
        }
    }

    // W = sigmoid(logit)*rcp(max(denom,EPS)) -> WB (bf16, swizzled).
    // 16 dword loads first (ILP), then trans math.
    {
        const float* lb = logits + (size_t)((n * Z_ + z) * Y_ + y0) * X_ + x0;
        float lgs[4][4];
        #pragma unroll
        for (int nt = 0; nt < 4; ++nt)
            #pragma unroll
            for (int reg = 0; reg < 4; ++reg)
                lgs[nt][reg] = lb[(w * 16 + quad * 4 + reg) * X_ + nt * 16 + m];
        #pragma unroll
        for (int nt = 0; nt < 4; ++nt) {
            #pragma unroll
            for (int reg = 0; reg < 4; ++reg) {
                int yl = w * 16 + quad * 4 + reg;
                int xl = nt * 16 + m;
                float wv = 1.0f / ((1.0f + __expf(-lgs[nt][reg])) *
                                   fmaxf(acc1[nt][reg], EPSF));
                WB[yl * 64 + (((xl >> 3) ^ (yl & 7)) * 8) + (xl & 7)] = bf16(wv);
            }
        }
    }

    // GEMM2 A-frags (kx row p = w*16+m, x-half) analytically: 16 exps/lane.
    v8s a2[2];
    {
        float px = ptsn[(w * 16 + m) * 3 + 2];
        #pragma unroll
        for (int ks = 0; ks < 2; ++ks) {
            #pragma unroll
            for (int j = 0; j < 8; ++j) {
                float dx = (float)(x0 + ks * 32 + quad * 8 + j) - px;
                a2[ks][j] = bf16(__expf(-dx * dx * INV2S2));
            }
        }
    }
    __syncthreads();                   // WB ready

    // GEMM2: wave w -> M-tile w (p), N-tiles 0..3 (y), K = 2 steps (x-local).
    v4f acc2[4];
    #pragma unroll
    for (int nt = 0; nt < 4; ++nt) acc2[nt] = (v4f)(0.f);
    #pragma unroll
    for (int ks = 0; ks < 2; ++ks) {
        #pragma unroll
        for (int nt = 0; nt < 4; ++nt) {
            int row = nt * 16 + m;     // y-local
            int c = ks * 4 + quad;     // x-chunk
            v8s bf = *(const v8s*)&WB[row * 64 + ((c ^ (row & 7)) * 8)];
            acc2[nt] = __builtin_amdgcn_mfma_f32_16x16x32_bf16(a2[ks], bf, acc2[nt], 0, 0, 0);
        }
    }

    // Epilogue: s[reg] = sum_nt kzy[y][p]*D2[p][y]; p = w*16+quad*4+reg,
    // y = y0+nt*16+m (analytic kzy, 16 exps/lane); reduce over the 16
    // m-lanes; atomicAdd into poison-biased m (no fence, no part[] trip).
    float s[4] = {0.f, 0.f, 0.f, 0.f};
    #pragma unroll
    for (int reg = 0; reg < 4; ++reg) {
        int p = w * 16 + quad * 4 + reg;
        float pz = ptsn[p * 3 + 0], py = ptsn[p * 3 + 1];
        float dz = (float)z - pz;
        #pragma unroll
        for (int nt = 0; nt < 4; ++nt) {
            float dy = (float)(y0 + nt * 16 + m) - py;
            float kzy = __expf(-(dz * dz + dy * dy) * INV2S2);
            s[reg] = fmaf(acc2[nt][reg], kzy, s[reg]);
        }
    }
    #pragma unroll
    for (int reg = 0; reg < 4; ++reg)
        #pragma unroll
        for (int off = 1; off < 16; off <<= 1)
            s[reg] += __shfl_xor(s[reg], off, 64);
    if (m == 0) {
        #pragma unroll
        for (int reg = 0; reg < 4; ++reg)
            atomicAdd(&mAcc[n * 64 + w * 16 + quad * 4 + reg], s[reg]);
    }
}

// ---------------------------------------------------------------------------
// Finish: loss = mean_{n,p} -log(max(m, EPS)). 1 block x 256 threads, 1 KB
// read (L2-hot). Kernel boundary provides coherence for the atomics — no
// fence anywhere (R8: fence-finish cost +23 us).
// ---------------------------------------------------------------------------
__global__ __launch_bounds__(256) void k_finish(const float* __restrict__ mAcc,
                                                float* __restrict__ out) {
    const int t = threadIdx.x;
    float l = -logf(fmaxf(mAcc[t], EPSF));
    #pragma unroll
    for (int off = 32; off > 0; off >>= 1) l += __shfl_xor(l, off, 64);
    __shared__ float red[4];
    if ((t & 63) == 0) red[t >> 6] = l;
    __syncthreads();
    if (t == 0) out[0] = (red[0] + red[1] + red[2] + red[3]) * (1.0f / 256.0f);
}

extern "C" void kernel_launch(void* const* d_in, const int* in_sizes, int n_in,
                              void* d_out, int out_size, void* d_ws, size_t ws_size,
                              hipStream_t stream) {
    const float* logits = (const float*)d_in[0];  // [4,1,32,128,128] fp32
    const float* pts    = (const float*)d_in[1];  // [4,64,3] fp32
    float* mAcc = (float*)d_ws;                   // m[256]; 0xAA base = -3e-13
    float* out  = (float*)d_out;                  // scalar fp32

    k_main<<<dim3(512), dim3(256), 0, stream>>>(logits, pts, mAcc);
    k_finish<<<dim3(1), dim3(256), 0, stream>>>(mAcc, out);
}

// Round 12
// 66.905 us; speedup vs baseline: 1.1225x; 1.1225x over previous
//
#include <hip/hip_runtime.h>
#include <math.h>

// Problem constants (fixed by reference)
constexpr int N_ = 4, P_ = 64, Z_ = 32, Y_ = 128, X_ = 128;
constexpr float EPSF = 1e-8f;
constexpr float INV2S2 = 0.125f;   // 1/(2*sigma^2), sigma = 2

typedef short v8s __attribute__((ext_vector_type(8)));  // 8 bf16 (4 VGPRs)
typedef float v4f __attribute__((ext_vector_type(4)));  // MFMA C/D

// fp32 -> bf16 (RNE). bf16 keeps fp32's exponent: no far-field flush (w can
// be ~1e8 and K ~1e-30; both representable). R10 measured absmax 0.0.
__device__ __forceinline__ short bf16(float f) {
    unsigned u = __float_as_uint(f);
    u = u + 0x7fffu + ((u >> 16) & 1u);
    return (short)(u >> 16);
}

// ---------------------------------------------------------------------------
// MFMA main kernel — R10 structure VERBATIM (best measured: 66.0 us) with
// ONE change: the 32 logit loads are hoisted to the top of the kernel so
// their ~600-900 cyc latency hides behind ptsn staging + kx staging + GEMM1
// instead of being eaten serially between GEMM1 and the W-phase.
//
// R11 lessons baked in: NO device-scope atomics into shared lines (32768
// atomicAdds onto 16 cache lines ping-ponged across 8 XCDs => +9 us) and
// NO x-split (duplicates a-frag/epilogue exp work). Private part[] slots,
// full-overwrite (poison-proof), 2 dispatches (R8: fence finish +23 us).
//
// Grid: 256 blocks = (n, z, y-half); 256 threads = 4 waves.
// Per block (y-slab 64 x full 128 x):
//   GEMM1 (mfma 16x16x32 bf16): denom[y][x] = sum_p kzy[y][p]*kx[p][x]
//   W = sigmoid(logit)/max(denom,EPS) -> bf16 LDS (layout transform)
//   GEMM2: D2[p][y] = sum_x kx[p][x]*W[y][x]
//   s[p] = sum_y kzy[y][p]*D2[p][y] (analytic kzy, in-register)
// Fragment layouts (HW-verified): A[m=lane&15][k=quad*8+j], C/D col=lane&15,
// row=quad*4+reg. kx/W tiles XOR-chunk-swizzled (c ^= row&N) -> <=2-way LDS
// aliasing on fragment reads.
// ---------------------------------------------------------------------------
__global__ __launch_bounds__(256) void k_main(const float* __restrict__ logits,
                                              const float* __restrict__ pts,
                                              float* __restrict__ part) {
    const int b = blockIdx.x;          // [n:2][z:5][yh:1]
    const int n  = b >> 6;
    const int z  = (b >> 1) & 31;
    const int y0 = (b & 1) * 64;

    const int tid  = threadIdx.x;
    const int lane = tid & 63;
    const int w    = tid >> 6;         // wave 0..3
    const int m    = lane & 15;        // row/col-in-tile index
    const int quad = lane >> 4;        // 0..3

    __shared__ float ptsn[192];        // pts[n] = [64][3]
    __shared__ short kxTB[128 * 64];   // [x][p] bf16, 8-chunk XOR swizzle
    __shared__ short WB[64 * 128];     // [y-local][x] bf16, 16-chunk swizzle
    __shared__ float psum[64];

    // ---- Hoisted logit loads: issue FIRST, consume in the W-phase. ----
    float lgs[8][4];
    {
        const float* lb = logits + (size_t)((n * Z_ + z) * Y_ + y0) * X_;
        #pragma unroll
        for (int nt = 0; nt < 8; ++nt)
            #pragma unroll
            for (int reg = 0; reg < 4; ++reg)
                lgs[nt][reg] = lb[(w * 16 + quad * 4 + reg) * 128 + nt * 16 + m];
    }

    if (tid < 192) ptsn[tid] = pts[n * 192 + tid];
    __syncthreads();

    // kx table: 8192 exps / 256 threads. Store at swizzled chunk.
    for (int i = tid; i < 128 * 64; i += 256) {
        int x = i >> 6, p = i & 63;
        float dx = (float)x - ptsn[p * 3 + 2];
        float e = __expf(-dx * dx * INV2S2);
        kxTB[x * 64 + (((p >> 3) ^ (x & 7)) * 8) + (p & 7)] = bf16(e);
    }

    // GEMM1 A-frags (kzy rows) analytically: 16 exps/lane (quad-uniform
    // ptsn reads broadcast).
    v8s a1[2];
    {
        float yv = (float)(y0 + w * 16 + m);
        #pragma unroll
        for (int ks = 0; ks < 2; ++ks) {
            #pragma unroll
            for (int j = 0; j < 8; ++j) {
                int p = ks * 32 + quad * 8 + j;
                float dz = (float)z - ptsn[p * 3 + 0];
                float dy = yv - ptsn[p * 3 + 1];
                a1[ks][j] = bf16(__expf(-(dz * dz + dy * dy) * INV2S2));
            }
        }
    }
    __syncthreads();                   // kxTB ready

    // GEMM1: wave w -> M-tile w (y), N-tiles 0..7 (x), K = 2 mfma steps (p).
    v4f acc1[8];
    #pragma unroll
    for (int nt = 0; nt < 8; ++nt) acc1[nt] = (v4f)(0.f);
    #pragma unroll
    for (int ks = 0; ks < 2; ++ks) {
        #pragma unroll
        for (int nt = 0; nt < 8; ++nt) {
            int row = nt * 16 + m;     // x
            int c = ks * 4 + quad;     // p-chunk
            v8s bf = *(const v8s*)&kxTB[row * 64 + ((c ^ (row & 7)) * 8)];
            acc1[nt] = __builtin_amdgcn_mfma_f32_16x16x32_bf16(a1[ks], bf, acc1[nt], 0, 0, 0);
        }
    }

    // W = sigmoid(logit)*rcp(max(denom,EPS)) -> WB (bf16, swizzled).
    // lgs already resident (hoisted loads) — pure VALU here.
    #pragma unroll
    for (int nt = 0; nt < 8; ++nt) {
        #pragma unroll
        for (int reg = 0; reg < 4; ++reg) {
            int yl = w * 16 + quad * 4 + reg;
            int x  = nt * 16 + m;
            float wv = 1.0f / ((1.0f + __expf(-lgs[nt][reg])) *
                               fmaxf(acc1[nt][reg], EPSF));
            WB[yl * 128 + (((x >> 3) ^ (yl & 15)) * 8) + (x & 7)] = bf16(wv);
        }
    }

    // GEMM2 A-frags (kx row p = w*16+m) analytically: 16 exps/lane.
    v8s a2[4];
    {
        float px = ptsn[(w * 16 + m) * 3 + 2];
        #pragma unroll
        for (int ks = 0; ks < 4; ++ks) {
            #pragma unroll
            for (int j = 0; j < 8; ++j) {
                float dx = (float)(ks * 32 + quad * 8 + j) - px;
                a2[ks][j] = bf16(__expf(-dx * dx * INV2S2));
            }
        }
    }
    __syncthreads();                   // WB ready

    // GEMM2: wave w -> M-tile w (p), N-tiles 0..3 (y), K = 4 mfma steps (x).
    v4f acc2[4];
    #pragma unroll
    for (int nt = 0; nt < 4; ++nt) acc2[nt] = (v4f)(0.f);
    #pragma unroll
    for (int ks = 0; ks < 4; ++ks) {
        #pragma unroll
        for (int nt = 0; nt < 4; ++nt) {
            int row = nt * 16 + m;     // y-local
            int c = ks * 4 + quad;     // x-chunk
            v8s bf = *(const v8s*)&WB[row * 128 + ((c ^ (row & 15)) * 8)];
            acc2[nt] = __builtin_amdgcn_mfma_f32_16x16x32_bf16(a2[ks], bf, acc2[nt], 0, 0, 0);
        }
    }

    // Epilogue: s[reg] = sum_nt kzy[y][p]*D2[p][y]; p = w*16+quad*4+reg,
    // y = y0+nt*16+m. kzy analytic (16 exps; quad-uniform ptsn broadcast).
    float s[4] = {0.f, 0.f, 0.f, 0.f};
    #pragma unroll
    for (int reg = 0; reg < 4; ++reg) {
        int p = w * 16 + quad * 4 + reg;
        float pz = ptsn[p * 3 + 0], py = ptsn[p * 3 + 1];
        float dz = (float)z - pz;
        #pragma unroll
        for (int nt = 0; nt < 4; ++nt) {
            float dy = (float)(y0 + nt * 16 + m) - py;
            float kzy = __expf(-(dz * dz + dy * dy) * INV2S2);
            s[reg] = fmaf(acc2[nt][reg], kzy, s[reg]);
        }
    }
    // Reduce over the 16 y-lanes (low 4 lane bits).
    #pragma unroll
    for (int reg = 0; reg < 4; ++reg)
        #pragma unroll
        for (int off = 1; off < 16; off <<= 1)
            s[reg] += __shfl_xor(s[reg], off, 64);
    if (m == 0) {
        #pragma unroll
        for (int reg = 0; reg < 4; ++reg)
            psum[w * 16 + quad * 4 + reg] = s[reg];
    }
    __syncthreads();
    if (tid < 64) part[b * 64 + tid] = psum[tid];   // private slot, no atomic
}

// ---------------------------------------------------------------------------
// Finish: m[n][p] = sum of that n's 64 block-partials; loss = mean(-log(...)).
// 1 block x 1024 threads: 4 threads per (n,p), 16 partials each, LDS combine.
// ---------------------------------------------------------------------------
__global__ __launch_bounds__(1024) void k_finish(const float* __restrict__ part,
                                                 float* __restrict__ out) {
    const int t = threadIdx.x;
    const int pair = t & 255;          // (n,p)
    const int quarter = t >> 8;        // 16-block slice
    const int n = pair >> 6, p = pair & 63;

    const float* base = part + (size_t)(n * 64 + quarter * 16) * 64 + p;
    float s0 = 0.f, s1 = 0.f, s2 = 0.f, s3 = 0.f;
    #pragma unroll
    for (int j = 0; j < 16; j += 4) {
        s0 += base[(j + 0) * 64];
        s1 += base[(j + 1) * 64];
        s2 += base[(j + 2) * 64];
        s3 += base[(j + 3) * 64];
    }
    __shared__ float red[4][256];
    red[quarter][pair] = (s0 + s1) + (s2 + s3);
    __syncthreads();

    if (t < 256) {
        const float mv = (red[0][t] + red[1][t]) + (red[2][t] + red[3][t]);
        float l = -logf(fmaxf(mv, EPSF));
        #pragma unroll
        for (int off = 32; off > 0; off >>= 1) l += __shfl_xor(l, off, 64);
        __shared__ float red2[4];
        if ((t & 63) == 0) red2[t >> 6] = l;
        __syncthreads();
        if (t == 0) out[0] = (red2[0] + red2[1] + red2[2] + red2[3]) * (1.0f / 256.0f);
    }
}

extern "C" void kernel_launch(void* const* d_in, const int* in_sizes, int n_in,
                              void* d_out, int out_size, void* d_ws, size_t ws_size,
                              hipStream_t stream) {
    const float* logits = (const float*)d_in[0];  // [4,1,32,128,128] fp32
    const float* pts    = (const float*)d_in[1];  // [4,64,3] fp32
    float* part = (float*)d_ws;                   // 256*64 floats = 64 KB
    float* out  = (float*)d_out;                  // scalar fp32

    k_main<<<dim3(256), dim3(256), 0, stream>>>(logits, pts, part);
    k_finish<<<dim3(1), dim3(1024), 0, stream>>>(part, out);
}